// Round 2
// baseline (5408.002 us; speedup 1.0000x reference)
//
#include <hip/hip_runtime.h>
#include <math.h>

// QuantumMambaSSMCore R2: 10-qubit state-vector scan, B=128, S=512.
//  - 2 waves/block, 8 amps/thread. Layout: phys bits {0,5,6}->reg, {1,2,3,4,7,8}->lane,
//    {9}->wave (bit 9 minimizes cross-wave gate count: 8/step).
//  - CNOTs folded into GF(2) masks (as R1). Phase A = direct product-state build (free).
//  - All 40 QSVT RZs fused into ONE per-amp phase (signed sum + 8-pt Walsh + sincos).
//  - Wave-local pair gates via __shfl_xor (no barrier); cross-wave via double-buffered
//    padded LDS stage (1 barrier/gate). 10 barriers/step vs 43 in R1.
//  - h-independent per-step tables (t_half, final-RY trig, C) precomputed by a parallel
//    kernel into d_ws (fallback: inline compute if ws too small).

#define PIF 3.14159265358979323846f

constexpr int NQ   = 10;
constexpr int SEQ  = 512;
constexpr int NB   = 128;
constexpr int NTHR = 128;
constexpr int RECF = 72;   // floats per (b,t) table record

struct CTbl {
  int vh[NQ], mh[NQ];
  int vz[4][NQ], mz[4][NQ];
  int vu[2][NQ], mu[2][NQ];
  int vf[NQ], mf[NQ];
  int zm[NQ];
};

constexpr CTbl build_tbl() {
  CTbl t{};
  unsigned mrow[NQ], vcol[NQ];
  for (int b = 0; b < NQ; ++b) { mrow[b] = 1u << b; vcol[b] = 1u << b; }
  for (int i = 0; i < NQ; ++i) { t.vh[i] = (int)vcol[9 - i]; t.mh[i] = (int)mrow[9 - i]; }
  for (int d = 0; d < 4; ++d) {
    for (int i = 0; i < NQ; ++i) { t.vz[d][i] = (int)vcol[9 - i]; t.mz[d][i] = (int)mrow[9 - i]; }
    for (int i = 0; i < NQ - 1; ++i) {
      int bc = 9 - i, bt = 8 - i;
      mrow[bt] ^= mrow[bc];
      vcol[bc] ^= vcol[bt];
    }
    { int bc = 0, bt = 9;
      mrow[bt] ^= mrow[bc];
      vcol[bc] ^= vcol[bt]; }
  }
  for (int l = 0; l < 2; ++l) {
    for (int i = 0; i < NQ; ++i) { t.vu[l][i] = (int)vcol[9 - i]; t.mu[l][i] = (int)mrow[9 - i]; }
    for (int i = 0; i < NQ - 1; ++i) {
      int bc = 9 - i, bt = 8 - i;
      mrow[bt] ^= mrow[bc];
      vcol[bc] ^= vcol[bt];
    }
  }
  for (int i = 0; i < NQ; ++i) { t.vf[i] = (int)vcol[9 - i]; t.mf[i] = (int)mrow[9 - i]; }
  for (int i = 0; i < NQ; ++i) t.zm[i] = (int)mrow[9 - i];
  return t;
}
constexpr CTbl CT = build_tbl();

// storage layout decomposition of a physical 10-bit mask
constexpr int regPart(int x)  { return ((x >> 0) & 1) | (((x >> 5) & 1) << 1) | (((x >> 6) & 1) << 2); }
constexpr int lanePart(int x) { return ((x >> 1) & 1) | (((x >> 2) & 1) << 1) | (((x >> 3) & 1) << 2) |
                                       (((x >> 4) & 1) << 3) | (((x >> 7) & 1) << 4) | (((x >> 8) & 1) << 5); }
constexpr int wavePart(int x) { return (x >> 9) & 1; }
constexpr int m7of(int x)     { return lanePart(x) | (wavePart(x) << 6); } // parity mask vs tid(0..127)

// ---------- precompute kernel: h-independent per-step tables ----------
__global__ __launch_bounds__(256) void qmamba_pre(
    const float* __restrict__ angles, const float* __restrict__ Wx,
    const float* __restrict__ Wdt, const float* __restrict__ bdt,
    const float* __restrict__ pc, float* __restrict__ tbl)
{
  int idx = blockIdx.x * 256 + threadIdx.x;        // (b*SEQ + t)
  if (idx >= NB * SEQ) return;
  const float* ar = angles + (size_t)idx * NQ;
  float a[NQ];
#pragma unroll
  for (int n = 0; n < NQ; ++n) a[n] = ar[n];
  float dtr[5];
#pragma unroll
  for (int r = 0; r < 5; ++r) {
    float acc = 0.f;
#pragma unroll
    for (int n = 0; n < NQ; ++n) acc += a[n] * Wx[r * NQ + n];
    dtr[r] = acc;
  }
  float pcr[4] = {pc[0], pc[1], pc[2], pc[3]};
  float* rec = tbl + (size_t)idx * RECF;
#pragma unroll
  for (int w = 0; w < NQ; ++w) {
    float lin = bdt[w];
#pragma unroll
    for (int r = 0; r < 5; ++r) lin += dtr[r] * Wdt[w * 5 + r];
    float sp = lin > 0.f ? lin + log1pf(__expf(-lin)) : log1pf(__expf(lin));
    float th = tanhf(sp) * PIF;                    // dt_angles
#pragma unroll
    for (int d = 0; d < 4; ++d) rec[d * 10 + w] = 0.5f * pcr[d] * th * PIF;
    float fa = 0.5f * a[w] * th;
    rec[40 + w] = __cosf(fa);
    rec[50 + w] = __sinf(fa);
    float Cv = 0.f;
#pragma unroll
    for (int n = 0; n < NQ; ++n) Cv += a[n] * Wx[(15 + w) * NQ + n];
    rec[60 + w] = Cv;
  }
}

// ---------- main scan kernel ----------
__global__ __launch_bounds__(NTHR) void qmamba_main(
    const float* __restrict__ angles, const float* __restrict__ Wx,
    const float* __restrict__ Wdt, const float* __restrict__ bdt,
    const float* __restrict__ pc, const float* __restrict__ cp,
    const float* __restrict__ Dg, const float* __restrict__ tbl,
    float* __restrict__ out)
{
  __shared__ float2 st[2][NTHR][9];     // cross-wave stage, +1 float2 pad (bank-safe)
  __shared__ float4 uu4[20][2];         // fused U: [0]={u00,u01}, [1]={u10,u11}
  __shared__ float2 hcs[NQ];            // (cos(h/2), sin(h/2))
  __shared__ float thalf[40];           // RZ half-angles, d-major
  __shared__ float fcl[NQ], fsl[NQ];    // final-RY cos/sin
  __shared__ float part[NQ][2];         // per-wave measurement partials

  const int tid  = threadIdx.x;
  const int b    = blockIdx.x;
  const int lane = tid & 63;
  const int wid  = tid >> 6;

  // fused variational unitaries U = RZ(g)*RY(be)*RX(al), once per launch
  if (tid < 20) {
    int k = tid * 3;
    float al = 0.5f * cp[k], be = 0.5f * cp[k + 1], ga = 0.5f * cp[k + 2];
    float ca = __cosf(al), sa = __sinf(al);
    float cb = __cosf(be), sb = __sinf(be);
    float cg = __cosf(ga), sg = __sinf(ga);
    float2 M00 = make_float2(cb * ca,  sb * sa);
    float2 M01 = make_float2(-sb * ca, -cb * sa);
    float2 M10 = make_float2(sb * ca,  -cb * sa);
    float2 M11 = make_float2(cb * ca,  -sb * sa);
    float2 e0 = make_float2(cg, -sg), e1 = make_float2(cg, sg);
    auto cm = [](float2 a, float2 c) {
      return make_float2(a.x * c.x - a.y * c.y, a.x * c.y + a.y * c.x);
    };
    float2 u00 = cm(M00, e0), u01 = cm(M01, e0), u10 = cm(M10, e1), u11 = cm(M11, e1);
    uu4[tid][0] = make_float4(u00.x, u00.y, u01.x, u01.y);
    uu4[tid][1] = make_float4(u10.x, u10.y, u11.x, u11.y);
  }

  float hreg = 0.f, Dreg = 0.f;
  float pcr[4] = {0.f, 0.f, 0.f, 0.f};
  if (tid < NQ) {
    Dreg = Dg[tid];
    if (!tbl) {
#pragma unroll
      for (int d = 0; d < 4; ++d) pcr[d] = pc[d];
    }
  }

  int sb = 0;
  float2 amp[8];

#pragma unroll 1
  for (int t = 0; t < SEQ; ++t) {
    const float* arow = angles + (size_t)(b * SEQ + t) * NQ;
    float Cv = 0.f, av = 0.f;

    if (tbl) {
      const float* rec = tbl + (size_t)(b * SEQ + t) * RECF;
      float tv = 0.f;
      if (tid < 60) tv = rec[tid];
      if (tid < NQ) { Cv = rec[60 + tid]; av = arow[tid]; }
      if (tid < 40)       thalf[tid] = tv;
      else if (tid < 50)  fcl[tid - 40] = tv;
      else if (tid < 60)  fsl[tid - 50] = tv;
    } else {
      if (tid < NQ) {
        float a[NQ];
#pragma unroll
        for (int n = 0; n < NQ; ++n) a[n] = arow[n];
        float dtr[5];
#pragma unroll
        for (int r = 0; r < 5; ++r) {
          float acc = 0.f;
#pragma unroll
          for (int n = 0; n < NQ; ++n) acc += a[n] * Wx[r * NQ + n];
          dtr[r] = acc;
        }
        Cv = 0.f;
#pragma unroll
        for (int n = 0; n < NQ; ++n) Cv += a[n] * Wx[(15 + tid) * NQ + n];
        float lin = bdt[tid];
#pragma unroll
        for (int r = 0; r < 5; ++r) lin += dtr[r] * Wdt[tid * 5 + r];
        float sp = lin > 0.f ? lin + log1pf(__expf(-lin)) : log1pf(__expf(lin));
        float th = tanhf(sp) * PIF;
#pragma unroll
        for (int d = 0; d < 4; ++d) thalf[d * 10 + tid] = 0.5f * pcr[d] * th * PIF;
        av = arow[tid];
        float fa = 0.5f * av * th;
        fcl[tid] = __cosf(fa);
        fsl[tid] = __sinf(fa);
      }
    }
    if (tid < NQ) {
      float sh, ch_;
      __sincosf(0.5f * hreg, &sh, &ch_);
      hcs[tid] = make_float2(ch_, sh);
    }
    __syncthreads();   // B: tables ready

    // ---- Phase A (free): real product state from RY(h)|0>
    float2 h9 = hcs[9], h4 = hcs[4], h3 = hcs[3];
    float F;
    {
      float2 h8 = hcs[8], h7 = hcs[7], h6 = hcs[6], h5 = hcs[5], h2 = hcs[2], h1 = hcs[1], h0 = hcs[0];
      F  = (lane & 1)  ? h8.y : h8.x;
      F *= (lane & 2)  ? h7.y : h7.x;
      F *= (lane & 4)  ? h6.y : h6.x;
      F *= (lane & 8)  ? h5.y : h5.x;
      F *= (lane & 16) ? h2.y : h2.x;
      F *= (lane & 32) ? h1.y : h1.x;
      F *= wid ? h0.y : h0.x;
    }

    // ---- Phase B (fused): one phase per amp from all 40 RZs
    float S[8] = {0.f, 0.f, 0.f, 0.f, 0.f, 0.f, 0.f, 0.f};
#pragma unroll
    for (int k = 0; k < 40; ++k) {
      const int m  = CT.mz[k / 10][k % 10];
      const int gr = regPart(m);
      const float th = thalf[k];
      const int par = __popc(tid & m7of(m)) & 1;
      S[gr] += par ? th : -th;
    }
#pragma unroll
    for (int bb = 1; bb < 8; bb <<= 1) {
#pragma unroll
      for (int g = 0; g < 8; ++g)
        if (!(g & bb)) { float x = S[g], y = S[g | bb]; S[g] = x + y; S[g | bb] = x - y; }
    }
#pragma unroll
    for (int r = 0; r < 8; ++r) {
      float P = F * ((r & 1) ? h9.y : h9.x) * ((r & 2) ? h4.y : h4.x) * ((r & 4) ? h3.y : h3.x);
      float sn, cs;
      __sincosf(S[r], &sn, &cs);
      amp[r] = make_float2(P * cs, P * sn);
    }

    // ---- pair-gate machinery
    auto fetch = [&](int v, float2* p) {
      const int vw = wavePart(v), vl = lanePart(v), vr = regPart(v);
      if (vw) {
#pragma unroll
        for (int r = 0; r < 8; ++r) st[sb][tid][r] = amp[r];
        __syncthreads();
        const int ptid = tid ^ 64 ^ vl;
#pragma unroll
        for (int r = 0; r < 8; ++r) p[r] = st[sb][ptid][r ^ vr];
        sb ^= 1;
      } else if (vl) {
#pragma unroll
        for (int r = 0; r < 8; ++r) {
          float2 a0 = amp[r ^ vr];
          p[r] = make_float2(__shfl_xor(a0.x, vl, 64), __shfl_xor(a0.y, vl, 64));
        }
      } else {
#pragma unroll
        for (int r = 0; r < 8; ++r) p[r] = amp[r ^ vr];
      }
    };

    auto gate_ry = [&](int v, int m, float c, float s) {
      float2 p[8];
      fetch(v, p);
      const int plw = __popc(tid & m7of(m)) & 1;
      const float sp_ = plw ? s : -s;         // partner sign for reg-parity-even amps
#pragma unroll
      for (int r = 0; r < 8; ++r) {
        const float se = (__popc(r & regPart(m)) & 1) ? -sp_ : sp_;
        amp[r].x = c * amp[r].x + se * p[r].x;
        amp[r].y = c * amp[r].y + se * p[r].y;
      }
    };

    auto gate_u = [&](int v, int m, int g) {
      float2 p[8];
      fetch(v, p);
      float4 U0 = uu4[g][0], U1 = uu4[g][1];
      const int plw = __popc(tid & m7of(m)) & 1;
      float2 A0 = plw ? make_float2(U1.z, U1.w) : make_float2(U0.x, U0.y);
      float2 B0 = plw ? make_float2(U1.x, U1.y) : make_float2(U0.z, U0.w);
      float2 A1 = plw ? make_float2(U0.x, U0.y) : make_float2(U1.z, U1.w);
      float2 B1 = plw ? make_float2(U0.z, U0.w) : make_float2(U1.x, U1.y);
#pragma unroll
      for (int r = 0; r < 8; ++r) {
        const bool pr = (__popc(r & regPart(m)) & 1) != 0;
        float2 A = pr ? A1 : A0, B = pr ? B1 : B0;
        float2 o = amp[r], q = p[r];
        amp[r].x = A.x * o.x - A.y * o.y + B.x * q.x - B.y * q.y;
        amp[r].y = A.x * o.y + A.y * o.x + B.x * q.y + B.y * q.x;
      }
    };

    // ---- Phase C: fused variational SU(2) layers (5 cross-wave barriers)
#pragma unroll
    for (int l = 0; l < 2; ++l) {
#pragma unroll
      for (int i = 0; i < NQ; ++i) gate_u(CT.vu[l][i], CT.mu[l][i], l * NQ + i);
    }
    // ---- Phase D: RY(x*dt) (3 cross-wave barriers)
#pragma unroll
    for (int i = 0; i < NQ; ++i) gate_ry(CT.vf[i], CT.mf[i], fcl[i], fsl[i]);

    // ---- measurement
    float q[8];
#pragma unroll
    for (int r = 0; r < 8; ++r) q[r] = amp[r].x * amp[r].x + amp[r].y * amp[r].y;
#pragma unroll
    for (int w = 0; w < NQ; ++w) {
      const int m = CT.zm[w];
      float tw = 0.f;
#pragma unroll
      for (int r = 0; r < 8; ++r) tw += (__popc(r & regPart(m)) & 1) ? -q[r] : q[r];
      if (__popc(tid & m7of(m)) & 1) tw = -tw;
#pragma unroll
      for (int k = 0; k < 6; ++k) tw += __shfl_xor(tw, 1 << k, 64);
      if (lane == 0) part[w][wid] = tw;
    }
    __syncthreads();   // C: partials ready
    if (tid < NQ) {
      float z = part[tid][0] + part[tid][1];
      out[(size_t)(b * SEQ + t) * NQ + tid] = Cv * z + Dreg * av;
      hreg = z;
    }
  }
}

extern "C" void kernel_launch(void* const* d_in, const int* in_sizes, int n_in,
                              void* d_out, int out_size, void* d_ws, size_t ws_size,
                              hipStream_t stream) {
  (void)in_sizes; (void)n_in; (void)out_size;
  const float* angles = (const float*)d_in[0];
  const float* Wx     = (const float*)d_in[1];
  const float* Wdt    = (const float*)d_in[2];
  const float* bdt    = (const float*)d_in[3];
  const float* pc     = (const float*)d_in[4];
  const float* cp     = (const float*)d_in[5];
  const float* Dg     = (const float*)d_in[6];
  float* out = (float*)d_out;

  float* tbl = nullptr;
  const size_t need = (size_t)NB * SEQ * RECF * sizeof(float);
  if (ws_size >= need) {
    tbl = (float*)d_ws;
    hipLaunchKernelGGL(qmamba_pre, dim3((NB * SEQ + 255) / 256), dim3(256), 0, stream,
                       angles, Wx, Wdt, bdt, pc, tbl);
  }
  hipLaunchKernelGGL(qmamba_main, dim3(NB), dim3(NTHR), 0, stream,
                     angles, Wx, Wdt, bdt, pc, cp, Dg, tbl, out);
}